// Round 3
// baseline (524.873 us; speedup 1.0000x reference)
//
#include <hip/hip_runtime.h>

// NonLocalBlock3D collapsed form:
//   S[b] = X Xt (256x256), s[b] = rowsum(X)
//   kv   = phi_w S g_wT + (phi_w s) g_bT + phi_b (g_w s)T + N phi_b g_bT
//   M'   = I + W_w kvT theta_w / N   (256x256, per batch, bf16; identity folded)
//   c    = W_w kvT theta_b / N + W_b
//   out  = M' x + c        (residual folded into M')
#define NB 2
#define CC 256
#define CI 128
#define NN 65536
#define LDA 72        // 64 + 8 pad (bf16), 144B row stride
#define LDX 264       // 256 + 8 pad (bf16) for out-kernel transposed tile

typedef __bf16 bf16x8 __attribute__((ext_vector_type(8)));
typedef float f32x4 __attribute__((ext_vector_type(4)));

__device__ __forceinline__ unsigned short f2bf(float f) {
  unsigned u = __float_as_uint(f);
  u += 0x7fffu + ((u >> 16) & 1u);   // RNE; inputs finite
  return (unsigned short)(u >> 16);
}

// ---------------- Kernel A: full-tile SYRK, split-K partials, reg-prefetch ---
__global__ __launch_bounds__(512) void nl3d_syrk2(const float* __restrict__ x,
                                                  float* __restrict__ S,
                                                  float* __restrict__ partials,
                                                  float* __restrict__ svec,
                                                  int kchunk, int use_partial) {
  __shared__ unsigned short lds[256 * LDA];   // 36 KB
  const int tid = threadIdx.x;
  const int lane = tid & 63;
  const int wv = tid >> 6;                    // 0..7
  const int wm = wv & 3, wn = wv >> 2;        // 4x2 wave grid: 64 x 128 per wave
  const int b = blockIdx.y;
  const int kc0 = blockIdx.x * kchunk;

  const float* xb = x + (size_t)b * CC * NN;
  f32x4 acc[4][8];
  const f32x4 zero4 = {0.f, 0.f, 0.f, 0.f};
#pragma unroll
  for (int i = 0; i < 4; ++i)
#pragma unroll
    for (int j = 0; j < 8; ++j) acc[i][j] = zero4;

  float rsum[8];
#pragma unroll
  for (int i = 0; i < 8; ++i) rsum[i] = 0.f;

  const int r0 = tid >> 4;    // 0..31
  const int c4 = tid & 15;
  const int m = lane & 15;
  const int kg = (lane >> 4) * 8;

  float4 fX0[8], fX1[8];
  auto loadf = [&](float4* f, int kc) {
#pragma unroll
    for (int i = 0; i < 8; ++i)
      f[i] = *(const float4*)(xb + (size_t)(r0 + 32 * i) * NN + kc + c4 * 4);
  };
  auto storef = [&](const float4* f) {
#pragma unroll
    for (int i = 0; i < 8; ++i) {
      int row = r0 + 32 * i;
      ushort4 h;
      h.x = f2bf(f[i].x); h.y = f2bf(f[i].y); h.z = f2bf(f[i].z); h.w = f2bf(f[i].w);
      *(ushort4*)&lds[row * LDA + c4 * 4] = h;
      rsum[i] += f[i].x + f[i].y + f[i].z + f[i].w;
    }
  };
  auto mfma_blk = [&]() {
#pragma unroll
    for (int kk = 0; kk < 2; ++kk) {
      bf16x8 afr[4], bfr[8];
#pragma unroll
      for (int mt = 0; mt < 4; ++mt)
        afr[mt] = *(const bf16x8*)&lds[(wm * 64 + mt * 16 + m) * LDA + kk * 32 + kg];
#pragma unroll
      for (int nt = 0; nt < 8; ++nt)
        bfr[nt] = *(const bf16x8*)&lds[(wn * 128 + nt * 16 + m) * LDA + kk * 32 + kg];
#pragma unroll
      for (int mt = 0; mt < 4; ++mt)
#pragma unroll
        for (int nt = 0; nt < 8; ++nt)
          acc[mt][nt] = __builtin_amdgcn_mfma_f32_16x16x32_bf16(afr[mt], bfr[nt], acc[mt][nt], 0, 0, 0);
    }
  };

  const int stages = kchunk >> 6;   // even (>= 8)
  loadf(fX0, kc0);
  for (int s = 0; s < stages; s += 2) {
    __syncthreads();
    storef(fX0);
    if (s + 1 < stages) loadf(fX1, kc0 + (s + 1) * 64);
    __syncthreads();
    mfma_blk();
    __syncthreads();
    storef(fX1);
    if (s + 2 < stages) loadf(fX0, kc0 + (s + 2) * 64);
    __syncthreads();
    mfma_blk();
  }

  const int col = lane & 15;
  const int rq = (lane >> 4) * 4;
  if (use_partial) {
    float* dst = partials + ((size_t)(b * gridDim.x + blockIdx.x)) * (CC * CC);
#pragma unroll
    for (int mt = 0; mt < 4; ++mt)
#pragma unroll
      for (int nt = 0; nt < 8; ++nt)
#pragma unroll
        for (int r = 0; r < 4; ++r) {
          int gi = wm * 64 + mt * 16 + rq + r;
          int gj = wn * 128 + nt * 16 + col;
          dst[gi * CC + gj] = acc[mt][nt][r];
        }
  } else {
    float* Sb = S + (size_t)b * CC * CC;
#pragma unroll
    for (int mt = 0; mt < 4; ++mt)
#pragma unroll
      for (int nt = 0; nt < 8; ++nt)
#pragma unroll
        for (int r = 0; r < 4; ++r) {
          int gi = wm * 64 + mt * 16 + rq + r;
          int gj = wn * 128 + nt * 16 + col;
          atomicAdd(&Sb[gi * CC + gj], acc[mt][nt][r]);
        }
  }

  // rowsums -> svec (svec pre-zeroed)
  __syncthreads();
  float* ldsRS = (float*)lds;
  if (tid < 256) ldsRS[tid] = 0.f;
  __syncthreads();
#pragma unroll
  for (int i = 0; i < 8; ++i) atomicAdd(&ldsRS[r0 + 32 * i], rsum[i]);
  __syncthreads();
  if (tid < 256) atomicAdd(&svec[b * CC + tid], ldsRS[tid]);
}

// ---------------- fused chain: reduce + transpose + b1..b4, grid barrier -----
#define CHAIN_BLOCKS 256
__device__ __forceinline__ void grid_barrier(unsigned* cnt, int phase) {
  __syncthreads();
  if (threadIdx.x == 0) {
    __threadfence();
    unsigned arrived = atomicAdd(&cnt[phase], 1u) + 1u;
    if (arrived < (unsigned)CHAIN_BLOCKS) {
      while (atomicAdd(&cnt[phase], 0u) < (unsigned)CHAIN_BLOCKS)
        __builtin_amdgcn_s_sleep(1);
    }
    __threadfence();
  }
  __syncthreads();
}

__global__ __launch_bounds__(256) void nl3d_chain(
    const float* __restrict__ partials, float* __restrict__ S,
    const float* __restrict__ svec,
    const float* __restrict__ g_w, float* __restrict__ gwT,
    const float* __restrict__ phi_w, const float* __restrict__ phi_b,
    const float* __restrict__ g_b,
    const float* __restrict__ theta_w, const float* __restrict__ theta_b,
    const float* __restrict__ W_w, const float* __restrict__ W_b,
    float* __restrict__ P, float* __restrict__ kv, float* __restrict__ T2,
    float* __restrict__ tb2, unsigned short* __restrict__ Mbf,
    float* __restrict__ cvec, unsigned* __restrict__ cnt, int splits) {
  const int tid = threadIdx.x;
  const int bi = blockIdx.x;
  const int gtid = bi * 256 + tid;
  __shared__ float red[256];

  // ---- P0a: reduce split-K partials -> S (one float4 column per thread) ----
  if (splits > 0 && gtid < 32768) {
    const int b = gtid >> 14, off = gtid & 16383;
    const float4* p = (const float4*)partials;
    const size_t base = (size_t)b * splits * 16384 + off;
    float4 a0 = {0,0,0,0}, a1 = {0,0,0,0}, a2 = {0,0,0,0}, a3 = {0,0,0,0};
    for (int s = 0; s < splits; s += 4) {
      float4 v0 = p[base + (size_t)(s + 0) * 16384];
      float4 v1 = p[base + (size_t)(s + 1) * 16384];
      float4 v2 = p[base + (size_t)(s + 2) * 16384];
      float4 v3 = p[base + (size_t)(s + 3) * 16384];
      a0.x += v0.x; a0.y += v0.y; a0.z += v0.z; a0.w += v0.w;
      a1.x += v1.x; a1.y += v1.y; a1.z += v1.z; a1.w += v1.w;
      a2.x += v2.x; a2.y += v2.y; a2.z += v2.z; a2.w += v2.w;
      a3.x += v3.x; a3.y += v3.y; a3.z += v3.z; a3.w += v3.w;
    }
    float4 r;
    r.x = (a0.x + a1.x) + (a2.x + a3.x);
    r.y = (a0.y + a1.y) + (a2.y + a3.y);
    r.z = (a0.z + a1.z) + (a2.z + a3.z);
    r.w = (a0.w + a1.w) + (a2.w + a3.w);
    ((float4*)S)[gtid] = r;
  }
  // ---- P0b: transpose g_w -> gwT (other half of threads) ----
  if (gtid >= 32768) {
    int t = gtid - 32768;                  // t = j*256 + d
    gwT[(t & 255) * CI + (t >> 8)] = g_w[t];
  }
  grid_barrier(cnt, 0);

  // ---- P1: P[b,i,:] = phi_w[i,:] . S[b] ----
  {
    const int b = bi >> 7, i = bi & 127, d = tid;
    const float* Sb = S + (size_t)b * CC * CC;
    const float* ph = phi_w + i * CC;
    float a0 = 0, a1 = 0, a2 = 0, a3 = 0, a4 = 0, a5 = 0, a6 = 0, a7 = 0;
    for (int c = 0; c < CC; c += 8) {
      a0 += ph[c + 0] * Sb[(c + 0) * CC + d];
      a1 += ph[c + 1] * Sb[(c + 1) * CC + d];
      a2 += ph[c + 2] * Sb[(c + 2) * CC + d];
      a3 += ph[c + 3] * Sb[(c + 3) * CC + d];
      a4 += ph[c + 4] * Sb[(c + 4) * CC + d];
      a5 += ph[c + 5] * Sb[(c + 5) * CC + d];
      a6 += ph[c + 6] * Sb[(c + 6) * CC + d];
      a7 += ph[c + 7] * Sb[(c + 7) * CC + d];
    }
    P[((size_t)b * CI + i) * CC + d] = ((a0 + a1) + (a2 + a3)) + ((a4 + a5) + (a6 + a7));
  }
  grid_barrier(cnt, 1);

  // ---- P2: kv[b,i,:] ----
  {
    const int b = bi >> 7, i = bi & 127;
    if (tid < 128) {
      const int j = tid;
      const float* Pr = P + ((size_t)b * CI + i) * CC;
      const float* sv = svec + b * CC;
      const float* ph = phi_w + i * CC;
      float u0 = 0, u1 = 0;
      for (int c = 0; c < CC; c += 2) { u0 += ph[c] * sv[c]; u1 += ph[c + 1] * sv[c + 1]; }
      float a0 = 0, a1 = 0, a2 = 0, a3 = 0, v0 = 0, v1 = 0, v2 = 0, v3 = 0;
      for (int d = 0; d < CC; d += 4) {
        float g0 = gwT[(d + 0) * CI + j], g1 = gwT[(d + 1) * CI + j];
        float g2 = gwT[(d + 2) * CI + j], g3 = gwT[(d + 3) * CI + j];
        a0 += Pr[d + 0] * g0; a1 += Pr[d + 1] * g1; a2 += Pr[d + 2] * g2; a3 += Pr[d + 3] * g3;
        v0 += sv[d + 0] * g0; v1 += sv[d + 1] * g1; v2 += sv[d + 2] * g2; v3 += sv[d + 3] * g3;
      }
      kv[((size_t)b * CI + i) * CI + j] =
          ((a0 + a1) + (a2 + a3)) + (u0 + u1) * g_b[j] +
          phi_b[i] * (((v0 + v1) + (v2 + v3)) + (float)NN * g_b[j]);
    }
  }
  grid_barrier(cnt, 2);

  // ---- P3: T2[b,j,:] = kv[b,:,j]^T theta_w ; tb2[b,j] = kv[b,:,j].theta_b ----
  {
    const int b = bi >> 7, j = bi & 127, c = tid;
    const float* kvb = kv + (size_t)b * CI * CI;
    float a0 = 0, a1 = 0, a2 = 0, a3 = 0;
    for (int i = 0; i < CI; i += 4) {
      a0 += kvb[(i + 0) * CI + j] * theta_w[(i + 0) * CC + c];
      a1 += kvb[(i + 1) * CI + j] * theta_w[(i + 1) * CC + c];
      a2 += kvb[(i + 2) * CI + j] * theta_w[(i + 2) * CC + c];
      a3 += kvb[(i + 3) * CI + j] * theta_w[(i + 3) * CC + c];
    }
    T2[((size_t)b * CI + j) * CC + c] = (a0 + a1) + (a2 + a3);
    // parallel tb2 via LDS reduction
    red[tid] = (tid < CI) ? kvb[tid * CI + j] * theta_b[tid] : 0.f;
    __syncthreads();
    for (int s = 64; s > 0; s >>= 1) {
      if (tid < s) red[tid] += red[tid + s];
      __syncthreads();
    }
    if (tid == 0) tb2[b * CI + j] = red[0];
    __syncthreads();
  }
  grid_barrier(cnt, 3);

  // ---- P4: M' = I + W_w T2 / N (bf16), cvec = W_w tb2 / N + W_b ----
  {
    const float inv = 1.0f / (float)NN;
#pragma unroll
    for (int oo = 0; oo < 2; ++oo) {
      const int idx = bi * 2 + oo;
      const int b = idx >> 8, o = idx & 255, c = tid;
      const float* Wr = W_w + o * CI;
      float a0 = 0, a1 = 0, a2 = 0, a3 = 0;
      for (int j = 0; j < CI; j += 4) {
        a0 += Wr[j + 0] * T2[((size_t)b * CI + j + 0) * CC + c];
        a1 += Wr[j + 1] * T2[((size_t)b * CI + j + 1) * CC + c];
        a2 += Wr[j + 2] * T2[((size_t)b * CI + j + 2) * CC + c];
        a3 += Wr[j + 3] * T2[((size_t)b * CI + j + 3) * CC + c];
      }
      float mval = ((a0 + a1) + (a2 + a3)) * inv + (o == c ? 1.0f : 0.0f);
      Mbf[((size_t)b * CC + o) * CC + c] = f2bf(mval);
      red[tid] = (tid < CI) ? Wr[tid] * tb2[b * CI + tid] : 0.f;
      __syncthreads();
      for (int s = 64; s > 0; s >>= 1) {
        if (tid < s) red[tid] += red[tid + s];
        __syncthreads();
      }
      if (tid == 0) cvec[b * CC + o] = red[0] * inv + W_b[o];
      __syncthreads();
    }
  }
}

// ---------------- Kernel C: out = M' x + c, 4 tiles/block, dbuf + prefetch ---
__global__ __launch_bounds__(256, 2) void nl3d_out(const float* __restrict__ x,
                                                   const unsigned short* __restrict__ Mbf,
                                                   const float* __restrict__ cvec,
                                                   float* __restrict__ out) {
  __shared__ unsigned short xT[2][64 * LDX];
  const int tid = threadIdx.x;
  const int lane = tid & 63;
  const int wv = tid >> 6;
  const int b = blockIdx.y;
  const int n_base = blockIdx.x * 256;

  const float* xb = x + (size_t)b * CC * NN;
  float* ob = out + (size_t)b * CC * NN;
  const unsigned short* Mb = Mbf + (size_t)b * CC * CC;

  const int c4 = tid & 15;
  const int pr = tid >> 4;          // 0..15
  const int m = lane & 15;
  const int kg = (lane >> 4) * 8;
  const int col = lane & 15;
  const int rquad = (lane >> 4) * 4;

  float cvf[4][4];
#pragma unroll
  for (int mt = 0; mt < 4; ++mt)
#pragma unroll
    for (int r = 0; r < 4; ++r)
      cvf[mt][r] = cvec[b * CC + wv * 64 + mt * 16 + rquad + r];

  float4 fa[2][8], fb[2][8];
  auto load_tile = [&](int t, int buf) {
    const int n0 = n_base + t * 64;
#pragma unroll
    for (int i = 0; i < 8; ++i) {
      const int p = i * 16 + pr;
      fa[buf][i] = *(const float4*)(xb + (size_t)(2 * p) * NN + n0 + c4 * 4);
      fb[buf][i] = *(const float4*)(xb + (size_t)(2 * p + 1) * NN + n0 + c4 * 4);
    }
  };

  load_tile(0, 0);
  const f32x4 zero4 = {0.f, 0.f, 0.f, 0.f};

#pragma unroll
  for (int t = 0; t < 4; ++t) {
    const int buf = t & 1;
    __syncthreads();               // xT[buf] readers from iter t-2 are done
    // convert + transposed store (swizzled)
#pragma unroll
    for (int i = 0; i < 8; ++i) {
      const int p = i * 16 + pr;
      const int ps = p ^ ((c4 & 7) << 2);
      float A0[4] = {fa[buf][i].x, fa[buf][i].y, fa[buf][i].z, fa[buf][i].w};
      float A1[4] = {fb[buf][i].x, fb[buf][i].y, fb[buf][i].z, fb[buf][i].w};
#pragma unroll
      for (int j = 0; j < 4; ++j) {
        unsigned pack = (unsigned)f2bf(A0[j]) | ((unsigned)f2bf(A1[j]) << 16);
        *(unsigned*)&xT[buf][(c4 * 4 + j) * LDX + 2 * ps] = pack;
      }
    }
    if (t < 3) load_tile(t + 1, buf ^ 1);   // in flight across MFMA + stores
    __syncthreads();

    f32x4 acc[4][4];
#pragma unroll
    for (int i = 0; i < 4; ++i)
#pragma unroll
      for (int j = 0; j < 4; ++j) acc[i][j] = zero4;

#pragma unroll
    for (int kc = 0; kc < 8; ++kc) {
      bf16x8 afr[4], bfr[4];
#pragma unroll
      for (int mt = 0; mt < 4; ++mt)
        afr[mt] = *(const bf16x8*)(Mb + (size_t)(wv * 64 + mt * 16 + m) * CC + kc * 32 + kg);
#pragma unroll
      for (int nt = 0; nt < 4; ++nt) {
        const int rr = nt * 16 + m;
        const int d0 = (kc * 16 + (kg >> 1)) ^ (((rr >> 2) & 7) << 2);
        bfr[nt] = *(const bf16x8*)&xT[buf][rr * LDX + 2 * d0];
      }
#pragma unroll
      for (int mt = 0; mt < 4; ++mt)
#pragma unroll
        for (int nt = 0; nt < 4; ++nt)
          acc[mt][nt] = __builtin_amdgcn_mfma_f32_16x16x32_bf16(afr[mt], bfr[nt], acc[mt][nt], 0, 0, 0);
    }

    const int n0 = n_base + t * 64;
#pragma unroll
    for (int mt = 0; mt < 4; ++mt)
#pragma unroll
      for (int r = 0; r < 4; ++r) {
        const int o = wv * 64 + mt * 16 + rquad + r;
        float* orow = ob + (size_t)o * NN + n0;
        const float cv = cvf[mt][r];
#pragma unroll
        for (int nt = 0; nt < 4; ++nt)
          orow[nt * 16 + col] = acc[mt][nt][r] + cv;   // residual folded into M'
      }
  }
}

extern "C" void kernel_launch(void* const* d_in, const int* in_sizes, int n_in,
                              void* d_out, int out_size, void* d_ws, size_t ws_size,
                              hipStream_t stream) {
  const float* x       = (const float*)d_in[0];
  const float* g_w     = (const float*)d_in[1];
  const float* g_b     = (const float*)d_in[2];
  const float* theta_w = (const float*)d_in[3];
  const float* theta_b = (const float*)d_in[4];
  const float* phi_w   = (const float*)d_in[5];
  const float* phi_b   = (const float*)d_in[6];
  const float* W_w     = (const float*)d_in[7];
  const float* W_b     = (const float*)d_in[8];
  float* out = (float*)d_out;

  char* ws = (char*)d_ws;
  float* S    = (float*)(ws);                          // 512 KiB
  float* svec = (float*)(ws + 524288);                 // 2 KiB
  float* P    = (float*)(ws + 526336);                 // 256 KiB
  float* gwT  = (float*)(ws + 788480);                 // 128 KiB
  float* kv   = (float*)(ws + 919552);                 // 128 KiB
  float* T2   = (float*)(ws + 1050624);                // 256 KiB
  float* tb2  = (float*)(ws + 1312768);                // 1 KiB
  unsigned short* Mbf = (unsigned short*)(ws + 1313792); // 256 KiB
  float* cvec = (float*)(ws + 1575936);                // 2 KiB
  unsigned* cnt = (unsigned*)(ws + 1577984);           // barrier counters (256 B)
  float* partials = (float*)(ws + 2097152);            // NB*splits*256KiB

  int splits = 0;
  for (int c = 128; c >= 8; c >>= 1) {
    if (2097152 + (size_t)NB * c * CC * CC * 4 <= ws_size) { splits = c; break; }
  }

  if (splits > 0) {
    // zero svec + intermediates + barrier counters (1 MB, one call)
    hipMemsetAsync(ws + 524288, 0, 1578240 - 524288, stream);
    nl3d_syrk2<<<dim3(splits, NB), 512, 0, stream>>>(x, S, partials, svec,
                                                     NN / splits, 1);
  } else {
    hipMemsetAsync(ws, 0, 1578240, stream);            // also zero S (atomic path)
    nl3d_syrk2<<<dim3(64, NB), 512, 0, stream>>>(x, S, (float*)ws, svec,
                                                 NN / 64, 0);
  }
  nl3d_chain<<<CHAIN_BLOCKS, 256, 0, stream>>>(
      partials, S, svec, g_w, gwT, phi_w, phi_b, g_b, theta_w, theta_b,
      W_w, W_b, P, kv, T2, tb2, Mbf, cvec, cnt, splits);
  nl3d_out<<<dim3(NN / 256, NB), 256, 0, stream>>>(x, Mbf, cvec, out);
}